// Round 6
// baseline (110.548 us; speedup 1.0000x reference)
//
#include <hip/hip_runtime.h>

#define EPS 1e-5f
constexpr int NBLK = 512;
constexpr float INV_N1 = 1.f / 524288.f;   // D*U*2
constexpr float INV_N3 = 1.f / 262144.f;   // D*U

__device__ __forceinline__ float lrelu(float y) { return fmaxf(y, 0.01f * y); }

template <int CTRL>
__device__ __forceinline__ float dppMov(float v) {
    return __int_as_float(__builtin_amdgcn_update_dpp(
        0, __float_as_int(v), CTRL, 0xF, 0xF, true));
}
// sum within each 16-lane row; valid at lane%16==15
__device__ __forceinline__ float rowSumDpp(float v) {
    v += dppMov<0x111>(v);
    v += dppMov<0x112>(v);
    v += dppMov<0x114>(v);
    v += dppMov<0x118>(v);
    return v;
}
__device__ __forceinline__ float waveAllSum(float v) {
    v += __shfl_xor(v, 32); v += __shfl_xor(v, 16); v += __shfl_xor(v, 8);
    v += __shfl_xor(v, 4);  v += __shfl_xor(v, 2);  v += __shfl_xor(v, 1);
    return v;
}
// device-coherent (IF-point) read of data published via atomics
__device__ __forceinline__ float aload(const float* p) {
    return __hip_atomic_load(p, __ATOMIC_RELAXED, __HIP_MEMORY_SCOPE_AGENT);
}

// F-region float offsets (all memset-zeroed each launch; write via atomicAdd only)
#define F_M    0        // [64]  LN0 mean
#define F_RS   64       // [64]  LN0 rsqrt
#define F_RS1  128      // [64]  LN1 rs
#define F_MM1  192      // [64]  LN1 m*rs
#define F_XS   256      // [64]  sum xn
#define F_S1   320      // [512] per-d weight sums
#define F_S2   832
#define F_S11  1344
#define F_S0B  1856
#define F_SB2  2368
#define F_G3S  2880     // [512]
#define F_BE3S 3392     // [512]
#define F_ST2  4096     // 128 slots * 16 (64B padded)
#define F_ST3  6144     // 128 slots * 16
#define F_PQ   8192     // [64][512]
#define F_TOTAL 40960   // floats

struct SmP2 { float xcol[64], scA[64], scB[64]; float2 red2[64][4][4]; };
struct SmP3 { float mv[64], rv[64]; float4 sc4[64]; float sxn[64][32]; float2 qacc[4][4][64]; };

struct KArgs {
    const float *x, *w1, *b1, *w21, *w22, *b21, *b22, *w3, *b3, *bias;
    const float *g0, *be0, *g1, *be1, *g2, *be2, *g3, *be3;
    float* out;
    unsigned int* ctr;   // [4]
    float* F;
};

struct Wt { float2 W1, B1, G1, E1, A, C, G2, E2, W3; float Ba, Bc, B3, G3v; };

__device__ __forceinline__ void softBarrier(unsigned int* ctr, int k, int tid) {
    __syncthreads();   // drains this block's vmem (incl. fire-and-forget atomics)
    if (tid == 0) {
        __hip_atomic_fetch_add(&ctr[k], 1u, __ATOMIC_RELAXED, __HIP_MEMORY_SCOPE_AGENT);
        int guard = 0;
        while (__hip_atomic_load(&ctr[k], __ATOMIC_RELAXED, __HIP_MEMORY_SCOPE_AGENT) < (unsigned)NBLK
               && guard < 5000000) {
            __builtin_amdgcn_s_sleep(8);
            ++guard;
        }
    }
    __syncthreads();
}

__global__ void __launch_bounds__(256, 4) fused2(KArgs a) {
    const int bid = blockIdx.x, tid = threadIdx.x;
    const int wave = tid >> 6, lane = tid & 63;
    float* F = a.F;
    __shared__ __align__(16) char smraw[sizeof(SmP3)];
    __shared__ float red[4][5];
    __shared__ float bc[4];
    SmP2& s2m = *reinterpret_cast<SmP2*>(smraw);
    SmP3& s3m = *reinterpret_cast<SmP3*>(smraw);

    // ===== P0: per-d w1/b1 sums (all blocks); blocks<64 also g3/be3 cols =====
    {
        int d = bid;
        const float4* wr = (const float4*)(a.w1 + d * 1024);
        const float4* br = (const float4*)(a.b1 + d * 1024);
        float4 w = wr[tid], b = br[tid];
        float s1  = w.x + w.y + w.z + w.w;
        float ss2 = w.x * w.x + w.y * w.y + w.z * w.z + w.w * w.w;
        float s11 = w.x * b.x + w.y * b.y + w.z * b.z + w.w * b.w;
        float s0  = b.x + b.y + b.z + b.w;
        float sb2 = b.x * b.x + b.y * b.y + b.z * b.z + b.w * b.w;
        s1 = waveAllSum(s1); ss2 = waveAllSum(ss2); s11 = waveAllSum(s11);
        s0 = waveAllSum(s0); sb2 = waveAllSum(sb2);
        if (lane == 0) {
            red[wave][0] = s1; red[wave][1] = ss2; red[wave][2] = s11;
            red[wave][3] = s0; red[wave][4] = sb2;
        }
        __syncthreads();
        if (tid == 0) {
            float a0 = 0, a1 = 0, a2 = 0, a3 = 0, a4 = 0;
            for (int w4 = 0; w4 < 4; ++w4) {
                a0 += red[w4][0]; a1 += red[w4][1]; a2 += red[w4][2];
                a3 += red[w4][3]; a4 += red[w4][4];
            }
            unsafeAtomicAdd(&F[F_S1 + d], a0);
            unsafeAtomicAdd(&F[F_S2 + d], a1);
            unsafeAtomicAdd(&F[F_S11 + d], a2);
            unsafeAtomicAdd(&F[F_S0B + d], a3);
            unsafeAtomicAdd(&F[F_SB2 + d], a4);
        }
        if (bid < 64) {
            float ag0 = 0, ag1 = 0, ab0 = 0, ab1 = 0;
#pragma unroll
            for (int r = 0; r < 8; ++r) {
                const float* gr = a.g3 + (bid * 8 + r) * 512;
                const float* br2 = a.be3 + (bid * 8 + r) * 512;
                ag0 += gr[tid];  ag1 += gr[tid + 256];
                ab0 += br2[tid]; ab1 += br2[tid + 256];
            }
            unsafeAtomicAdd(&F[F_G3S + tid], ag0);
            unsafeAtomicAdd(&F[F_G3S + tid + 256], ag1);
            unsafeAtomicAdd(&F[F_BE3S + tid], ab0);
            unsafeAtomicAdd(&F[F_BE3S + tid + 256], ab1);
        }
    }
    softBarrier(a.ctr, 0, tid);

    // ===== P1: blocks<64: LN0 stats + xn row (local) + analytic LN1 stats ===
    if (bid < 64) {
        int b = bid;
        float2 xv = ((const float2*)(a.x + b * 512))[tid];
        float sx = xv.x + xv.y, sxx = xv.x * xv.x + xv.y * xv.y;
        sx = waveAllSum(sx); sxx = waveAllSum(sxx);
        if (lane == 0) { red[wave][0] = sx; red[wave][1] = sxx; }
        __syncthreads();
        if (tid == 0) {
            float s = red[0][0] + red[1][0] + red[2][0] + red[3][0];
            float c = red[0][1] + red[1][1] + red[2][1] + red[3][1];
            float m = s * (1.f / 512.f);
            float var = c * (1.f / 512.f) - m * m;
            bc[0] = m; bc[1] = rsqrtf(var + EPS);
        }
        __syncthreads();
        float m = bc[0], rsd = bc[1];
        float2 g = ((const float2*)a.g0)[tid], be = ((const float2*)a.be0)[tid];
        float xn0 = (xv.x - m) * rsd * g.x + be.x;
        float xn1 = (xv.y - m) * rsd * g.y + be.y;
        int d0 = 2 * tid, d1 = 2 * tid + 1;
        float s1a = aload(&F[F_S1 + d0]),  s1b = aload(&F[F_S1 + d1]);
        float s2a = aload(&F[F_S2 + d0]),  s2b = aload(&F[F_S2 + d1]);
        float sca = aload(&F[F_S11 + d0]), scb = aload(&F[F_S11 + d1]);
        float sba = aload(&F[F_S0B + d0]), sbb = aload(&F[F_S0B + d1]);
        float sqa = aload(&F[F_SB2 + d0]), sqb = aload(&F[F_SB2 + d1]);
        float pm = fmaf(xn0, s1a, sba) + fmaf(xn1, s1b, sbb);
        float pe = xn0 * xn0 * s2a + 2.f * xn0 * sca + sqa
                 + xn1 * xn1 * s2b + 2.f * xn1 * scb + sqb;
        float sxn = xn0 + xn1;
        pm = waveAllSum(pm); pe = waveAllSum(pe); sxn = waveAllSum(sxn);
        __syncthreads();
        if (lane == 0) { red[wave][0] = pm; red[wave][1] = pe; red[wave][2] = sxn; }
        __syncthreads();
        if (tid == 0) {
            float s = red[0][0] + red[1][0] + red[2][0] + red[3][0];
            float c = red[0][1] + red[1][1] + red[2][1] + red[3][1];
            float xs = red[0][2] + red[1][2] + red[2][2] + red[3][2];
            float m1 = s * INV_N1, e1 = c * INV_N1;
            float r = rsqrtf(e1 - m1 * m1 + EPS);
            unsafeAtomicAdd(&F[F_RS1 + b], r);
            unsafeAtomicAdd(&F[F_MM1 + b], m1 * r);
            unsafeAtomicAdd(&F[F_XS + b], xs);
            unsafeAtomicAdd(&F[F_M + b], m);
            unsafeAtomicAdd(&F[F_RS + b], rsd);
        }
    }
    softBarrier(a.ctr, 1, tid);

    // ===== P2: LN2 stat partials. d = bid; u in {tid, tid+256} ==============
    {
        int d = bid;
        if (tid < 64) {
            float mb = aload(&F[F_M + tid]), rb = aload(&F[F_RS + tid]);
            float xv = a.x[tid * 512 + d];
            s2m.xcol[tid] = (xv - mb) * rb * a.g0[d] + a.be0[d];
            s2m.scA[tid] = aload(&F[F_RS1 + tid]);
            s2m.scB[tid] = aload(&F[F_MM1 + tid]);
        }
        int i0 = d * 512 + tid, i1 = i0 + 256;
        float2 W1a = ((const float2*)a.w1)[i0], B1a = ((const float2*)a.b1)[i0];
        float2 G1a = ((const float2*)a.g1)[i0], E1a = ((const float2*)a.be1)[i0];
        float2 Aa  = ((const float2*)a.w21)[i0], Ca = ((const float2*)a.w22)[i0];
        float Baa = a.b21[i0], Bca = a.b22[i0];
        float2 W1b = ((const float2*)a.w1)[i1], B1b = ((const float2*)a.b1)[i1];
        float2 G1b = ((const float2*)a.g1)[i1], E1b = ((const float2*)a.be1)[i1];
        float2 Ab  = ((const float2*)a.w21)[i1], Cb = ((const float2*)a.w22)[i1];
        float Bab = a.b21[i1], Bcb = a.b22[i1];
        __syncthreads();
        for (int b = 0; b < 64; ++b) {
            float xd = s2m.xcol[b], r1 = s2m.scA[b], mmv = s2m.scB[b];
            float t0 = fmaf(xd, W1a.x, B1a.x), t1 = fmaf(xd, W1a.y, B1a.y);
            float z0 = fmaf(t0, r1, -mmv), z1 = fmaf(t1, r1, -mmv);
            float y0 = fmaf(z0, G1a.x, E1a.x), y1 = fmaf(z1, G1a.y, E1a.y);
            float l0 = lrelu(y0), l1 = lrelu(y1);
            float c0 = fmaf(l0, Aa.x, fmaf(l1, Aa.y, Baa));
            float c1 = fmaf(l0, Ca.x, fmaf(l1, Ca.y, Bca));
            float v1 = c0 + c1;
            float v2 = fmaf(c0, c0, c1 * c1);
            t0 = fmaf(xd, W1b.x, B1b.x); t1 = fmaf(xd, W1b.y, B1b.y);
            z0 = fmaf(t0, r1, -mmv); z1 = fmaf(t1, r1, -mmv);
            y0 = fmaf(z0, G1b.x, E1b.x); y1 = fmaf(z1, G1b.y, E1b.y);
            l0 = lrelu(y0); l1 = lrelu(y1);
            c0 = fmaf(l0, Ab.x, fmaf(l1, Ab.y, Bab));
            c1 = fmaf(l0, Cb.x, fmaf(l1, Cb.y, Bcb));
            v1 += c0 + c1;
            v2 = fmaf(c0, c0, fmaf(c1, c1, v2));
            v1 = rowSumDpp(v1);
            v2 = rowSumDpp(v2);
            if ((lane & 15) == 15)
                s2m.red2[b][wave][lane >> 4] = make_float2(v1, v2);
        }
        __syncthreads();
        if (tid < 128) {   // tid = b*2+k
            int b = tid >> 1, k = tid & 1;
            float s = 0;
#pragma unroll
            for (int w = 0; w < 4; ++w)
#pragma unroll
                for (int r = 0; r < 4; ++r)
                    s += ((const float*)&s2m.red2[b][w][r])[k];
            unsafeAtomicAdd(&F[F_ST2 + tid * 16], s);
        }
    }
    softBarrier(a.ctr, 2, tid);

    // ===== P3: main fused pass. bd=bid>>5 (16 tiles of 32d), bu=bid&31 ======
    {
        int bd = bid >> 5, bu = bid & 31;
        int dloc = lane & 15, uloc = wave * 4 + (lane >> 4);
        int u = bu * 16 + uloc;
        if (tid < 64) {
            s3m.mv[tid] = aload(&F[F_M + tid]);
            s3m.rv[tid] = aload(&F[F_RS + tid]);
            float ssum = aload(&F[F_ST2 + (tid * 2) * 16]);
            float s2sum = aload(&F[F_ST2 + (tid * 2 + 1) * 16]);
            float mm = ssum * INV_N1;
            float var = s2sum * INV_N1 - mm * mm;
            float r2 = rsqrtf(var + EPS);
            s3m.sc4[tid] = make_float4(aload(&F[F_RS1 + tid]), aload(&F[F_MM1 + tid]),
                                       r2, mm * r2);
        }
        Wt wt[2];
#pragma unroll
        for (int j = 0; j < 2; ++j) {
            int d = bd * 32 + dloc + 16 * j;
            int i = d * 512 + u;
            wt[j].W1 = ((const float2*)a.w1)[i];  wt[j].B1 = ((const float2*)a.b1)[i];
            wt[j].G1 = ((const float2*)a.g1)[i];  wt[j].E1 = ((const float2*)a.be1)[i];
            wt[j].A  = ((const float2*)a.w21)[i]; wt[j].C  = ((const float2*)a.w22)[i];
            wt[j].G2 = ((const float2*)a.g2)[i];  wt[j].E2 = ((const float2*)a.be2)[i];
            wt[j].W3 = ((const float2*)a.w3)[i];
            wt[j].Ba = a.b21[i]; wt[j].Bc = a.b22[i]; wt[j].B3 = a.b3[i]; wt[j].G3v = a.g3[i];
        }
        __syncthreads();
        for (int idx = tid; idx < 2048; idx += 256) {
            int b = idx >> 5, dl = idx & 31, d = bd * 32 + dl;
            s3m.sxn[b][dl] = (a.x[b * 512 + d] - s3m.mv[b]) * s3m.rv[b] * a.g0[d] + a.be0[d];
        }
        __syncthreads();
        float* pq = &F[F_PQ];
        for (int b = 0; b < 64; ++b) {
            float4 s4 = s3m.sc4[b];   // rs1, m1*rs1, rs2, m2*rs2
            float p = 0, q = 0, q2 = 0;
#pragma unroll
            for (int j = 0; j < 2; ++j) {
                float xd = s3m.sxn[b][dloc + 16 * j];
                float t0 = fmaf(xd, wt[j].W1.x, wt[j].B1.x), t1 = fmaf(xd, wt[j].W1.y, wt[j].B1.y);
                float z0 = fmaf(t0, s4.x, -s4.y), z1 = fmaf(t1, s4.x, -s4.y);
                float y0 = fmaf(z0, wt[j].G1.x, wt[j].E1.x), y1 = fmaf(z1, wt[j].G1.y, wt[j].E1.y);
                float l0 = lrelu(y0), l1 = lrelu(y1);
                float c0 = fmaf(l0, wt[j].A.x, fmaf(l1, wt[j].A.y, wt[j].Ba));
                float c1 = fmaf(l0, wt[j].C.x, fmaf(l1, wt[j].C.y, wt[j].Bc));
                float z20 = fmaf(c0, s4.z, -s4.w), z21 = fmaf(c1, s4.z, -s4.w);
                float y20 = fmaf(z20, wt[j].G2.x, wt[j].E2.x), y21 = fmaf(z21, wt[j].G2.y, wt[j].E2.y);
                float m0 = lrelu(y20), m1v = lrelu(y21);
                float l3 = fmaf(m0, wt[j].W3.x, fmaf(m1v, wt[j].W3.y, wt[j].B3));
                p = fmaf(l3, wt[j].G3v, p); q += l3; q2 = fmaf(l3, l3, q2);
            }
            p = rowSumDpp(p); q = rowSumDpp(q); q2 = rowSumDpp(q2);
            if ((lane & 15) == 15) {
                unsafeAtomicAdd(&pq[b * 512 + u], p);
                s3m.qacc[wave][lane >> 4][b] = make_float2(q, q2);
            }
        }
        __syncthreads();
        if (tid < 128) {   // tid = b*2+k
            int b = tid >> 1, k = tid & 1;
            float s = 0;
#pragma unroll
            for (int w = 0; w < 4; ++w)
#pragma unroll
                for (int us = 0; us < 4; ++us)
                    s += ((const float*)&s3m.qacc[w][us][b])[k];
            unsafeAtomicAdd(&F[F_ST3 + tid * 16], s);
        }
    }
    softBarrier(a.ctr, 3, tid);

    // ===== P4: finalize (blocks < 64) =======================================
    if (bid < 64) {
        int b = bid;
        if (tid == 0) {
            float qq = aload(&F[F_ST3 + (2 * b) * 16]);
            float qq2 = aload(&F[F_ST3 + (2 * b + 1) * 16]);
            float m3 = qq * INV_N3, e3 = qq2 * INV_N3;
            bc[0] = m3;
            bc[1] = rsqrtf(e3 - m3 * m3 + EPS);
            bc[2] = aload(&F[F_XS + b]);
        }
        __syncthreads();
        float m3 = bc[0], rs3 = bc[1], xsb = bc[2];
        const float* pq = &F[F_PQ];
#pragma unroll
        for (int r = 0; r < 2; ++r) {
            int u = tid + r * 256;
            float p = aload(&pq[b * 512 + u]);
            float g = aload(&F[F_G3S + u]);
            float be = aload(&F[F_BE3S + u]);
            float val = rs3 * (p - m3 * g) + be + xsb + a.bias[u];
            a.out[b * 512 + u] = lrelu(val);
        }
    }
}

extern "C" void kernel_launch(void* const* d_in, const int* in_sizes, int n_in,
                              void* d_out, int out_size, void* d_ws, size_t ws_size,
                              hipStream_t stream) {
    char* ws = (char*)d_ws;
    KArgs ka;
    ka.x   = (const float*)d_in[0];
    ka.w1  = (const float*)d_in[1];
    ka.b1  = (const float*)d_in[2];
    ka.w21 = (const float*)d_in[3];
    ka.w22 = (const float*)d_in[4];
    ka.b21 = (const float*)d_in[5];
    ka.b22 = (const float*)d_in[6];
    ka.w3  = (const float*)d_in[7];
    ka.b3  = (const float*)d_in[8];
    ka.bias= (const float*)d_in[9];
    ka.g0  = (const float*)d_in[10];
    ka.be0 = (const float*)d_in[11];
    ka.g1  = (const float*)d_in[12];
    ka.be1 = (const float*)d_in[13];
    ka.g2  = (const float*)d_in[14];
    ka.be2 = (const float*)d_in[15];
    ka.g3  = (const float*)d_in[16];
    ka.be3 = (const float*)d_in[17];
    ka.out = (float*)d_out;
    ka.ctr = (unsigned int*)ws;          // 16 B
    ka.F   = (float*)(ws + 64);          // 40960 floats

    // zero counters + all atomic accumulators (one node, 164 KB)
    hipMemsetAsync(ws, 0, 64 + F_TOTAL * 4, stream);
    hipLaunchKernelGGL(fused2, dim3(NBLK), dim3(256), 0, stream, ka);
}

// Round 7
// 72.098 us; speedup vs baseline: 1.5333x; 1.5333x over previous
//
#include <hip/hip_runtime.h>

#define EPS 1e-5f
constexpr float INV_N1 = 1.f / 524288.f;   // D*U*2
constexpr float INV_N3 = 1.f / 262144.f;   // D*U

__device__ __forceinline__ float lrelu(float y) { return fmaxf(y, 0.01f * y); }

template <int CTRL>
__device__ __forceinline__ float dppMov(float v) {
    return __int_as_float(__builtin_amdgcn_update_dpp(
        0, __float_as_int(v), CTRL, 0xF, 0xF, true));
}
// sum within each 16-lane row; valid at lane%16==15
__device__ __forceinline__ float rowSumDpp(float v) {
    v += dppMov<0x111>(v);
    v += dppMov<0x112>(v);
    v += dppMov<0x114>(v);
    v += dppMov<0x118>(v);
    return v;
}
// sum over each 4-lane quad (all quad lanes get it)
__device__ __forceinline__ float quadSum(float v) {
    v += dppMov<0xB1>(v);   // quad_perm xor1
    v += dppMov<0x4E>(v);   // quad_perm xor2
    return v;
}
__device__ __forceinline__ float waveAllSum(float v) {
    v += __shfl_xor(v, 32); v += __shfl_xor(v, 16); v += __shfl_xor(v, 8);
    v += __shfl_xor(v, 4);  v += __shfl_xor(v, 2);  v += __shfl_xor(v, 1);
    return v;
}

// ---------------------------------------------------------------------------
// kW: 576 blocks. [0,512): per-d sums of w1/b1 -> S* (plain stores).
//     [512,576): partial column sums of g3/be3 -> Gp/Bp (plain stores).
// ---------------------------------------------------------------------------
__global__ void __launch_bounds__(256) kW(
    const float* __restrict__ w1, const float* __restrict__ b1,
    const float* __restrict__ g3, const float* __restrict__ be3,
    float* __restrict__ S1, float* __restrict__ S2, float* __restrict__ S11,
    float* __restrict__ S0b, float* __restrict__ Sb2,
    float* __restrict__ Gp, float* __restrict__ Bp) {
    int bid = blockIdx.x, tid = threadIdx.x;
    if (bid < 512) {
        const float4* wr = (const float4*)(w1 + bid * 1024);
        const float4* br = (const float4*)(b1 + bid * 1024);
        float4 w = wr[tid], b = br[tid];
        float s1  = w.x + w.y + w.z + w.w;
        float s2  = w.x * w.x + w.y * w.y + w.z * w.z + w.w * w.w;
        float s11 = w.x * b.x + w.y * b.y + w.z * b.z + w.w * b.w;
        float s0  = b.x + b.y + b.z + b.w;
        float sb2 = b.x * b.x + b.y * b.y + b.z * b.z + b.w * b.w;
        __shared__ float red[4][5];
        s1 = waveAllSum(s1); s2 = waveAllSum(s2); s11 = waveAllSum(s11);
        s0 = waveAllSum(s0); sb2 = waveAllSum(sb2);
        int wave = tid >> 6, lane = tid & 63;
        if (lane == 0) {
            red[wave][0] = s1; red[wave][1] = s2; red[wave][2] = s11;
            red[wave][3] = s0; red[wave][4] = sb2;
        }
        __syncthreads();
        if (tid == 0) {
            float a0 = 0, a1 = 0, a2 = 0, a3 = 0, a4 = 0;
            for (int w4 = 0; w4 < 4; ++w4) {
                a0 += red[w4][0]; a1 += red[w4][1]; a2 += red[w4][2];
                a3 += red[w4][3]; a4 += red[w4][4];
            }
            S1[bid] = a0; S2[bid] = a1; S11[bid] = a2;
            S0b[bid] = a3; Sb2[bid] = a4;
        }
    } else {
        int jj = bid - 512;   // 0..63, 8 d-rows each
        float ag0 = 0, ag1 = 0, ab0 = 0, ab1 = 0;
#pragma unroll
        for (int r = 0; r < 8; ++r) {
            const float* gr = g3 + (jj * 8 + r) * 512;
            const float* br = be3 + (jj * 8 + r) * 512;
            ag0 += gr[tid];  ag1 += gr[tid + 256];
            ab0 += br[tid];  ab1 += br[tid + 256];
        }
        Gp[jj * 512 + tid] = ag0; Gp[jj * 512 + tid + 256] = ag1;
        Bp[jj * 512 + tid] = ab0; Bp[jj * 512 + tid + 256] = ab1;
    }
}

// ---------------------------------------------------------------------------
// kB: 66 blocks. [0,64): LN0 per batch -> xn, Xs; analytic LN1 stats -> rs1a,
//     mm1a. [64]: fold Gp -> G3s. [65]: fold Bp -> Be3s.
// ---------------------------------------------------------------------------
__global__ void __launch_bounds__(256) kB(
    const float* __restrict__ x, const float* __restrict__ g0,
    const float* __restrict__ be0,
    const float* __restrict__ S1, const float* __restrict__ S2,
    const float* __restrict__ S11, const float* __restrict__ S0b,
    const float* __restrict__ Sb2,
    const float* __restrict__ Gp, const float* __restrict__ Bp,
    float* __restrict__ xnp, float* __restrict__ rs1a, float* __restrict__ mm1a,
    float* __restrict__ Xs, float* __restrict__ G3s, float* __restrict__ Be3s) {
    int bid = blockIdx.x, tid = threadIdx.x;
    if (bid < 64) {
        int b = bid;
        float2 xv = ((const float2*)(x + b * 512))[tid];
        float sx = xv.x + xv.y;
        float sxx = xv.x * xv.x + xv.y * xv.y;
        __shared__ float red[4][3];
        __shared__ float bc[2];
        sx = waveAllSum(sx); sxx = waveAllSum(sxx);
        int wave = tid >> 6, lane = tid & 63;
        if (lane == 0) { red[wave][0] = sx; red[wave][1] = sxx; }
        __syncthreads();
        if (tid == 0) {
            float a = red[0][0] + red[1][0] + red[2][0] + red[3][0];
            float c = red[0][1] + red[1][1] + red[2][1] + red[3][1];
            float m = a * (1.f / 512.f);
            float var = c * (1.f / 512.f) - m * m;
            bc[0] = m; bc[1] = rsqrtf(var + EPS);
        }
        __syncthreads();
        float m = bc[0], rsd = bc[1];
        float2 g = ((const float2*)g0)[tid];
        float2 be = ((const float2*)be0)[tid];
        float xn0 = (xv.x - m) * rsd * g.x + be.x;
        float xn1 = (xv.y - m) * rsd * g.y + be.y;
        ((float2*)(xnp + b * 512))[tid] = make_float2(xn0, xn1);
        float2 s1 = ((const float2*)S1)[tid], s0b = ((const float2*)S0b)[tid];
        float2 s2 = ((const float2*)S2)[tid], s11 = ((const float2*)S11)[tid];
        float2 sb2 = ((const float2*)Sb2)[tid];
        float pm = fmaf(xn0, s1.x, s0b.x) + fmaf(xn1, s1.y, s0b.y);
        float pe = xn0 * xn0 * s2.x + 2.f * xn0 * s11.x + sb2.x
                 + xn1 * xn1 * s2.y + 2.f * xn1 * s11.y + sb2.y;
        float sxn = xn0 + xn1;
        pm = waveAllSum(pm); pe = waveAllSum(pe); sxn = waveAllSum(sxn);
        __syncthreads();
        if (lane == 0) { red[wave][0] = pm; red[wave][1] = pe; red[wave][2] = sxn; }
        __syncthreads();
        if (tid == 0) {
            float a = red[0][0] + red[1][0] + red[2][0] + red[3][0];
            float c = red[0][1] + red[1][1] + red[2][1] + red[3][1];
            float s = red[0][2] + red[1][2] + red[2][2] + red[3][2];
            float m1 = a * INV_N1;
            float e1 = c * INV_N1;
            float r = rsqrtf(e1 - m1 * m1 + EPS);
            rs1a[b] = r; mm1a[b] = m1 * r; Xs[b] = s;
        }
    } else if (bid == 64) {
        for (int u = tid; u < 512; u += 256) {
            float s = 0;
#pragma unroll 8
            for (int jj = 0; jj < 64; ++jj) s += Gp[jj * 512 + u];
            G3s[u] = s;
        }
    } else {
        for (int u = tid; u < 512; u += 256) {
            float s = 0;
#pragma unroll 8
            for (int jj = 0; jj < 64; ++jj) s += Bp[jj * 512 + u];
            Be3s[u] = s;
        }
    }
}

// ---------------------------------------------------------------------------
// k1: LN2 stat partials. 512 blocks (d = bid), 2 u-slots per thread (ILP-2).
// rowSumDpp (8 DPP per batch) + LDS row-leader slots; end fold -> coalesced
// plain store part1[bid][128]  (slot = b*2+k).
// ---------------------------------------------------------------------------
__global__ void __launch_bounds__(256) k1(
    const float* __restrict__ w1, const float* __restrict__ b1,
    const float* __restrict__ g1, const float* __restrict__ be1,
    const float* __restrict__ w21, const float* __restrict__ w22,
    const float* __restrict__ b21, const float* __restrict__ b22,
    const float* __restrict__ xnp, const float* __restrict__ rs1a,
    const float* __restrict__ mm1a, float* __restrict__ part1) {
    int bid = blockIdx.x, tid = threadIdx.x;
    int d = bid;
    __shared__ float xcol[64], scA[64], scB[64];
    __shared__ float2 red2[64][4][4];   // [b][wave][row]
    if (tid < 64) {
        xcol[tid] = xnp[tid * 512 + d];
        scA[tid] = rs1a[tid];
        scB[tid] = mm1a[tid];
    }
    int i0 = d * 512 + tid, i1 = i0 + 256;
    float2 W1a = ((const float2*)w1)[i0], B1a = ((const float2*)b1)[i0];
    float2 G1a = ((const float2*)g1)[i0], E1a = ((const float2*)be1)[i0];
    float2 Aa  = ((const float2*)w21)[i0], Ca = ((const float2*)w22)[i0];
    float Baa = b21[i0], Bca = b22[i0];
    float2 W1b = ((const float2*)w1)[i1], B1b = ((const float2*)b1)[i1];
    float2 G1b = ((const float2*)g1)[i1], E1b = ((const float2*)be1)[i1];
    float2 Ab  = ((const float2*)w21)[i1], Cb = ((const float2*)w22)[i1];
    float Bab = b21[i1], Bcb = b22[i1];
    __syncthreads();
    int wave = tid >> 6, lane = tid & 63;
    for (int b = 0; b < 64; ++b) {
        float xd = xcol[b], r1 = scA[b], mmv = scB[b];
        float t0 = fmaf(xd, W1a.x, B1a.x), t1 = fmaf(xd, W1a.y, B1a.y);
        float z0 = fmaf(t0, r1, -mmv), z1 = fmaf(t1, r1, -mmv);
        float y0 = fmaf(z0, G1a.x, E1a.x), y1 = fmaf(z1, G1a.y, E1a.y);
        float l0 = lrelu(y0), l1 = lrelu(y1);
        float c0 = fmaf(l0, Aa.x, fmaf(l1, Aa.y, Baa));
        float c1 = fmaf(l0, Ca.x, fmaf(l1, Ca.y, Bca));
        float v1 = c0 + c1;
        float v2 = fmaf(c0, c0, c1 * c1);
        t0 = fmaf(xd, W1b.x, B1b.x); t1 = fmaf(xd, W1b.y, B1b.y);
        z0 = fmaf(t0, r1, -mmv); z1 = fmaf(t1, r1, -mmv);
        y0 = fmaf(z0, G1b.x, E1b.x); y1 = fmaf(z1, G1b.y, E1b.y);
        l0 = lrelu(y0); l1 = lrelu(y1);
        c0 = fmaf(l0, Ab.x, fmaf(l1, Ab.y, Bab));
        c1 = fmaf(l0, Cb.x, fmaf(l1, Cb.y, Bcb));
        v1 += c0 + c1;
        v2 = fmaf(c0, c0, fmaf(c1, c1, v2));
        v1 = rowSumDpp(v1);
        v2 = rowSumDpp(v2);
        if ((lane & 15) == 15)
            red2[b][wave][lane >> 4] = make_float2(v1, v2);
    }
    __syncthreads();
    if (tid < 128) {   // slot = b*2+k = tid
        int b = tid >> 1, k = tid & 1;
        float s = 0;
#pragma unroll
        for (int w = 0; w < 4; ++w)
#pragma unroll
            for (int r = 0; r < 4; ++r)
                s += ((const float*)&red2[b][w][r])[k];
        part1[bid * 128 + tid] = s;
    }
}

// ---------------------------------------------------------------------------
// k2: main fused pass. 512 blocks (bd 16 x bu 32). Prologue: redundant fold of
// part1[512][128] (L2-hot) -> LN2 stats. Main: 2 d's/thread, quadSum DPP,
// lane-private LDS accumulators (no in-loop barriers), plain partial stores.
// ---------------------------------------------------------------------------
struct Wt { float2 W1, B1, G1, E1, A, C, G2, E2, W3; float Ba, Bc, B3, G3v; };

__global__ void __launch_bounds__(256) k2(
    const float* __restrict__ w1, const float* __restrict__ b1,
    const float* __restrict__ g1, const float* __restrict__ be1,
    const float* __restrict__ w21, const float* __restrict__ w22,
    const float* __restrict__ b21, const float* __restrict__ b22,
    const float* __restrict__ g2, const float* __restrict__ be2,
    const float* __restrict__ w3, const float* __restrict__ b3,
    const float* __restrict__ g3,
    const float* __restrict__ xnp, const float* __restrict__ rs1a,
    const float* __restrict__ mm1a, const float* __restrict__ part1,
    float* __restrict__ pp, float* __restrict__ qp) {
    int bu = blockIdx.x & 31, bd = blockIdx.x >> 5, tid = threadIdx.x;
    int lane = tid & 63, wave = tid >> 6;
    int ul = (lane >> 2) & 15, d0 = lane & 3;
    int u = bu * 16 + ul;
    int dl0 = wave * 8 + d0 * 2;
    __shared__ float4 sc[64];
    __shared__ float sxn[64][32];
    __shared__ float comb[4][64][16][3];   // [wave][b][u][stat] 48 KB
    __shared__ float tmp2[2][128];
    // prologue part A: fold part1 (slot s over 512 k1-blocks, split 2 ways)
    {
        int s = tid & 127, half = tid >> 7;
        float acc = 0;
        const float* p = part1 + half * 256 * 128 + s;
#pragma unroll 8
        for (int blk = 0; blk < 256; ++blk) acc += p[blk * 128];
        tmp2[half][s] = acc;
    }
    {
        float* cz = &comb[0][0][0][0];
        for (int t = tid; t < 4 * 64 * 16 * 3; t += 256) cz[t] = 0.f;
    }
    for (int idx = tid; idx < 2048; idx += 256)
        sxn[idx >> 5][idx & 31] = xnp[(idx >> 5) * 512 + bd * 32 + (idx & 31)];
    Wt wt[2];
#pragma unroll
    for (int j = 0; j < 2; ++j) {
        int d = bd * 32 + dl0 + j;
        int i = d * 512 + u;
        wt[j].W1 = ((const float2*)w1)[i];  wt[j].B1 = ((const float2*)b1)[i];
        wt[j].G1 = ((const float2*)g1)[i];  wt[j].E1 = ((const float2*)be1)[i];
        wt[j].A  = ((const float2*)w21)[i]; wt[j].C  = ((const float2*)w22)[i];
        wt[j].G2 = ((const float2*)g2)[i];  wt[j].E2 = ((const float2*)be2)[i];
        wt[j].W3 = ((const float2*)w3)[i];
        wt[j].Ba = b21[i]; wt[j].Bc = b22[i]; wt[j].B3 = b3[i]; wt[j].G3v = g3[i];
    }
    __syncthreads();
    // prologue part B: LN2 stats per batch
    if (tid < 64) {
        float ssum = tmp2[0][2 * tid] + tmp2[1][2 * tid];
        float s2sum = tmp2[0][2 * tid + 1] + tmp2[1][2 * tid + 1];
        float mm = ssum * INV_N1;
        float var = s2sum * INV_N1 - mm * mm;
        float r2 = rsqrtf(var + EPS);
        sc[tid] = make_float4(rs1a[tid], mm1a[tid], r2, mm * r2);
    }
    __syncthreads();
    for (int b = 0; b < 64; ++b) {
        float4 s4 = sc[b];   // rs1, m1*rs1, rs2, m2*rs2
        float p = 0, q = 0, q2 = 0;
#pragma unroll
        for (int j = 0; j < 2; ++j) {
            float xd = sxn[b][dl0 + j];
            float t0 = fmaf(xd, wt[j].W1.x, wt[j].B1.x), t1 = fmaf(xd, wt[j].W1.y, wt[j].B1.y);
            float z0 = fmaf(t0, s4.x, -s4.y), z1 = fmaf(t1, s4.x, -s4.y);
            float y0 = fmaf(z0, wt[j].G1.x, wt[j].E1.x), y1 = fmaf(z1, wt[j].G1.y, wt[j].E1.y);
            float l0 = lrelu(y0), l1 = lrelu(y1);
            float c0 = fmaf(l0, wt[j].A.x, fmaf(l1, wt[j].A.y, wt[j].Ba));
            float c1 = fmaf(l0, wt[j].C.x, fmaf(l1, wt[j].C.y, wt[j].Bc));
            float z20 = fmaf(c0, s4.z, -s4.w), z21 = fmaf(c1, s4.z, -s4.w);
            float y20 = fmaf(z20, wt[j].G2.x, wt[j].E2.x), y21 = fmaf(z21, wt[j].G2.y, wt[j].E2.y);
            float m0 = lrelu(y20), m1v = lrelu(y21);
            float l3 = fmaf(m0, wt[j].W3.x, fmaf(m1v, wt[j].W3.y, wt[j].B3));
            p = fmaf(l3, wt[j].G3v, p); q += l3; q2 = fmaf(l3, l3, q2);
        }
        p = quadSum(p); q = quadSum(q); q2 = quadSum(q2);
        if (d0 < 3) {
            float v = (d0 == 0) ? p : ((d0 == 1) ? q : q2);
            comb[wave][b][ul][d0] += v;   // lane-private slot
        }
    }
    __syncthreads();
    // fold p over waves -> per-(b,u) partial for this bd (plain store)
#pragma unroll
    for (int r = 0; r < 4; ++r) {
        int idx = r * 256 + tid;
        int b = idx >> 4, uu = idx & 15;
        float s = comb[0][b][uu][0] + comb[1][b][uu][0]
                + comb[2][b][uu][0] + comb[3][b][uu][0];
        pp[(bd * 64 + b) * 512 + bu * 16 + uu] = s;
    }
    // fold q,q2 over waves AND u -> per-(block,b) scalars (plain store)
    if (tid < 128) {
        int b = tid >> 1, st = 1 + (tid & 1);
        float s = 0;
#pragma unroll
        for (int w = 0; w < 4; ++w)
#pragma unroll
            for (int uu = 0; uu < 16; ++uu) s += comb[w][b][uu][st];
        qp[(bd * 32 + bu) * 128 + b * 2 + (st - 1)] = s;
    }
}

// ---------------------------------------------------------------------------
// k3: LN3 stats from q-partials, fold p-partials, finalize output.
// ---------------------------------------------------------------------------
__global__ void __launch_bounds__(512) k3(
    const float* __restrict__ pp, const float* __restrict__ qp,
    const float* __restrict__ G3s, const float* __restrict__ Be3s,
    const float* __restrict__ Xs, const float* __restrict__ bias,
    float* __restrict__ out) {
    int b = blockIdx.x, u = threadIdx.x;
    float q  = qp[u * 128 + b * 2 + 0];
    float q2 = qp[u * 128 + b * 2 + 1];
    __shared__ float red[8][2];
    __shared__ float bc2[2];
    float sq = waveAllSum(q), sq2 = waveAllSum(q2);
    int wave = u >> 6, lane = u & 63;
    if (lane == 0) { red[wave][0] = sq; red[wave][1] = sq2; }
    __syncthreads();
    if (u == 0) {
        float a = 0, c = 0;
        for (int w = 0; w < 8; ++w) { a += red[w][0]; c += red[w][1]; }
        float m3 = a * INV_N3;
        float e3 = c * INV_N3;
        bc2[0] = m3; bc2[1] = rsqrtf(e3 - m3 * m3 + EPS);
    }
    __syncthreads();
    float p = 0;
#pragma unroll 4
    for (int bd = 0; bd < 16; ++bd) p += pp[(bd * 64 + b) * 512 + u];
    float m3 = bc2[0], rs3 = bc2[1];
    float val = rs3 * (p - m3 * G3s[u]) + Be3s[u] + Xs[b] + bias[u];
    out[b * 512 + u] = lrelu(val);
}

extern "C" void kernel_launch(void* const* d_in, const int* in_sizes, int n_in,
                              void* d_out, int out_size, void* d_ws, size_t ws_size,
                              hipStream_t stream) {
    const float* x   = (const float*)d_in[0];
    const float* w1  = (const float*)d_in[1];
    const float* b1  = (const float*)d_in[2];
    const float* w21 = (const float*)d_in[3];
    const float* w22 = (const float*)d_in[4];
    const float* b21 = (const float*)d_in[5];
    const float* b22 = (const float*)d_in[6];
    const float* w3  = (const float*)d_in[7];
    const float* b3  = (const float*)d_in[8];
    const float* bias= (const float*)d_in[9];
    const float* g0  = (const float*)d_in[10];
    const float* be0 = (const float*)d_in[11];
    const float* g1  = (const float*)d_in[12];
    const float* be1 = (const float*)d_in[13];
    const float* g2  = (const float*)d_in[14];
    const float* be2 = (const float*)d_in[15];
    const float* g3  = (const float*)d_in[16];
    const float* be3 = (const float*)d_in[17];
    float* out = (float*)d_out;
    char* ws = (char*)d_ws;

    float* xn    = (float*)(ws);             // 131072  [B][D]
    float* S1    = (float*)(ws + 131072);
    float* S2    = (float*)(ws + 133120);
    float* S11   = (float*)(ws + 135168);
    float* S0b   = (float*)(ws + 137216);
    float* Sb2   = (float*)(ws + 139264);
    float* rs1a  = (float*)(ws + 141312);
    float* mm1a  = (float*)(ws + 141568);
    float* Xs    = (float*)(ws + 141824);
    float* G3s   = (float*)(ws + 142080);    // 2048
    float* Be3s  = (float*)(ws + 144128);    // 2048
    float* Gp    = (float*)(ws + 146176);    // 131072 [64][512]
    float* Bp    = (float*)(ws + 277248);    // 131072
    float* part1 = (float*)(ws + 408320);    // 262144 [512][128]
    float* qp    = (float*)(ws + 670464);    // 262144 [512][128]
    float* pp    = (float*)(ws + 932608);    // 2097152 [16][64][512]

    hipLaunchKernelGGL(kW, dim3(576), dim3(256), 0, stream,
                       w1, b1, g3, be3, S1, S2, S11, S0b, Sb2, Gp, Bp);
    hipLaunchKernelGGL(kB, dim3(66), dim3(256), 0, stream,
                       x, g0, be0, S1, S2, S11, S0b, Sb2, Gp, Bp,
                       xn, rs1a, mm1a, Xs, G3s, Be3s);
    hipLaunchKernelGGL(k1, dim3(512), dim3(256), 0, stream,
                       w1, b1, g1, be1, w21, w22, b21, b22, xn, rs1a, mm1a, part1);
    hipLaunchKernelGGL(k2, dim3(512), dim3(256), 0, stream,
                       w1, b1, g1, be1, w21, w22, b21, b22, g2, be2, w3, b3, g3,
                       xn, rs1a, mm1a, part1, pp, qp);
    hipLaunchKernelGGL(k3, dim3(64), dim3(512), 0, stream,
                       pp, qp, G3s, Be3s, Xs, bias, out);
}